// Round 2
// baseline (70.030 us; speedup 1.0000x reference)
//
#include <hip/hip_runtime.h>
#include <hip/hip_bf16.h>
#include <stdint.h>

using f32x4  = __attribute__((ext_vector_type(4))) float;
using bf16x8 = __attribute__((ext_vector_type(8))) __bf16;
using u16x4  = __attribute__((ext_vector_type(4))) unsigned short;

#define DEVFN static __device__ __forceinline__

// ---------------- problem dims ----------------
constexpr int IND = 384, N1 = 512, N2R = 216, N2 = 256, NB = 10, NA = 2316;
constexpr int BATCH = 16384;
constexpr int RB  = 32;            // rows per block
constexpr int NC1 = 12;            // stage-1 K chunks (384/32)
constexpr int NC2 = 16;            // stage-2 K chunks (512/32)
constexpr int K3  = 224;           // stage-3 padded K (7 steps of 32)

// ---------------- ws layout (u16 elements) ----------------
// W1T: 12 chunks of [512 cols][32 k]  (pre-swizzled for conflict-reduced ds_read_b128)
// W2T: 16 chunks of [256 cols][32 k]  (cols >=216 zero)
// W3T: [16 cols][224 k]               (cols >=10, k >=216 zero)
// WhB: [10][2316] bf16 row-major
constexpr int WS_W1  = 0;
constexpr int WS_W2  = WS_W1 + NC1 * N1 * 32;   // 196608
constexpr int WS_W3  = WS_W2 + NC2 * N2 * 32;   // 327680
constexpr int WS_WH  = WS_W3 + 16 * K3;         // 331264
constexpr int WS_END = WS_WH + NB * NA;         // 354424

// ---------------- LDS layout (byte offsets), phase-reused ----------------
constexpr int XT_OFF  = 0;     constexpr int XT_ST = 784;   // [32][392] bf16 -> 25088
constexpr int W1C_OFF = 25088;                               // [512][32] bf16 -> 32768 (end 57856)
constexpr int H1_OFF  = 0;     constexpr int H1_ST = 1040;  // [32][520] bf16 -> 33280
constexpr int W2C_OFF = 33280;                               // [256][32] bf16 -> 16384 (end 49664)
constexpr int H2_OFF  = 0;     constexpr int H2_ST = 528;   // [32][264] bf16 -> 16896
constexpr int W3_OFF  = 16896; constexpr int W3_ST = 448;   // [16][224] bf16 -> 7168 (end 24064)
constexpr int WH_OFF  = 0;     constexpr int WH_ST = 4632;  // [10][2316] bf16 -> 46320
constexpr int BH_OFF  = 46320;                               // 2316 f32 -> 9264 (end 55584)
constexpr int F_OFF   = 55584; constexpr int F_ST  = 48;    // [32][12] f32 -> 1536 (end 57120)
constexpr int LDS_SZ  = 57856;

DEVFN unsigned short bf16u(float f) {
    __hip_bfloat16 h = __float2bfloat16(f);
    unsigned short u; __builtin_memcpy(&u, &h, 2); return u;
}

DEVFN bf16x8 ldsAB(const void* p) { return *(const bf16x8*)p; }

DEVFN void mfma16(f32x4& d, bf16x8 a, bf16x8 b) {
    d = __builtin_amdgcn_mfma_f32_16x16x32_bf16(a, b, d, 0, 0, 0);
}

DEVFN void gll16(const void* g, void* lds) {
    __builtin_amdgcn_global_load_lds((const __attribute__((address_space(1))) void*)g,
                                     (__attribute__((address_space(3))) void*)lds, 16, 0, 0);
}

// ============ pre-kernel: fp32 weights -> bf16, transposed/padded/swizzled ws image ============
__global__ __launch_bounds__(256)
void cvt_weights(const float* __restrict__ W1, const float* __restrict__ W2,
                 const float* __restrict__ W3, const float* __restrict__ Wh,
                 unsigned short* __restrict__ ws)
{
    int i = blockIdx.x * 256 + threadIdx.x;
    if (i >= WS_END) return;
    float v;
    if (i < WS_W2) {                       // W1T: chunk [512][32], swizzled
        int c = i >> 14, r = i & 16383;
        int col = r >> 5, s = r & 31;
        int k = c * 32 + (((s >> 3) ^ (col & 3)) << 3) + (s & 7);
        v = W1[k * N1 + col];
    } else if (i < WS_W3) {                // W2T: chunk [256][32], swizzled, col-pad
        int t = i - WS_W2;
        int c = t >> 13, r = t & 8191;
        int col = r >> 5, s = r & 31;
        int k = c * 32 + (((s >> 3) ^ (col & 3)) << 3) + (s & 7);
        v = (col < N2R) ? W2[k * N2R + col] : 0.f;
    } else if (i < WS_WH) {                // W3T: [16][224], swizzled, col/k-pad
        int t = i - WS_W3;
        int col = t / K3, s = t - col * K3;
        int sb = s >> 5, r = s & 31;
        int k = sb * 32 + (((r >> 3) ^ (col & 3)) << 3) + (r & 7);
        v = (col < NB && k < 216) ? W3[k * NB + col] : 0.f;
    } else {                               // Wh bf16, row-major
        v = Wh[i - WS_WH];
    }
    ws[i] = bf16u(v);
}

// ============ fused MLP: one block = 32 rows through all 4 layers ============
__global__ __launch_bounds__(256, 2)
void fused_mlp(const float* __restrict__ x,
               const float* __restrict__ b1g, const float* __restrict__ b2g,
               const float* __restrict__ b3g, const float* __restrict__ bhg,
               const unsigned short* __restrict__ ws,
               float* __restrict__ out)
{
    __shared__ __attribute__((aligned(16))) unsigned char smem[LDS_SZ];
    const int tid  = threadIdx.x;
    const int wave = tid >> 6;
    const int lane = tid & 63;
    const int l16  = lane & 15;
    const int lk   = lane >> 4;
    const int row0 = blockIdx.x * RB;

    // ---- stage x tile [32][384] f32 -> bf16 LDS [32][392] (fully coalesced) ----
    {
        const float4* xg = (const float4*)(x + (size_t)row0 * IND);
        #pragma unroll
        for (int i = 0; i < 12; ++i) {
            int j = tid + i * 256;          // 0..3071
            float4 v = xg[j];
            int el = j * 4, r = el / IND, c = el - r * IND;
            u16x4 h;
            h[0] = bf16u(v.x); h[1] = bf16u(v.y); h[2] = bf16u(v.z); h[3] = bf16u(v.w);
            *(u16x4*)(smem + XT_OFF + r * XT_ST + c * 2) = h;
        }
    }

    // per-wave bias registers
    float b1v[8], b2v[4], b3v;
    #pragma unroll
    for (int n = 0; n < 8; ++n) b1v[n] = b1g[wave * 128 + n * 16 + l16];
    #pragma unroll
    for (int n = 0; n < 4; ++n) {
        int col = wave * 64 + n * 16 + l16;
        b2v[n] = (col < N2R) ? b2g[col] : 0.f;
    }
    b3v = (l16 < NB) ? b3g[l16] : 0.f;

    // ================= Stage 1: h1 = relu(x @ W1 + b1) =================
    f32x4 acc1[2][8] = {};

    for (int c = 0; c < NC1; ++c) {
        __syncthreads();
        const unsigned short* src = ws + WS_W1 + c * (N1 * 32);
        for (int o = wave; o < 32; o += 4)
            gll16((const unsigned char*)src + o * 1024 + lane * 16, smem + W1C_OFF + o * 1024);
        __syncthreads();
        const int k0 = c * 32;
        bf16x8 a0 = ldsAB(smem + XT_OFF + (l16)      * XT_ST + (k0 + lk * 8) * 2);
        bf16x8 a1 = ldsAB(smem + XT_OFF + (16 + l16) * XT_ST + (k0 + lk * 8) * 2);
        #pragma unroll
        for (int n = 0; n < 8; ++n) {
            int col = wave * 128 + n * 16 + l16;
            bf16x8 b = ldsAB(smem + W1C_OFF + col * 64 + ((lk ^ (col & 3)) << 4));
            mfma16(acc1[0][n], a0, b);
            mfma16(acc1[1][n], a1, b);
        }
    }
    __syncthreads();
    #pragma unroll
    for (int m = 0; m < 2; ++m)
        #pragma unroll
        for (int n = 0; n < 8; ++n) {
            int col = wave * 128 + n * 16 + l16;
            #pragma unroll
            for (int e = 0; e < 4; ++e) {
                float v = fmaxf(acc1[m][n][e] + b1v[n], 0.f);
                *(unsigned short*)(smem + H1_OFF + (m * 16 + lk * 4 + e) * H1_ST + col * 2) = bf16u(v);
            }
        }

    // ================= Stage 2: h2 = relu(h1 @ W2 + b2), N padded to 256 =================
    f32x4 acc2[2][4] = {};

    for (int c = 0; c < NC2; ++c) {
        __syncthreads();
        const unsigned short* src = ws + WS_W2 + c * (N2 * 32);
        for (int o = wave; o < 16; o += 4)
            gll16((const unsigned char*)src + o * 1024 + lane * 16, smem + W2C_OFF + o * 1024);
        __syncthreads();
        const int k0 = c * 32;
        bf16x8 a0 = ldsAB(smem + H1_OFF + (l16)      * H1_ST + (k0 + lk * 8) * 2);
        bf16x8 a1 = ldsAB(smem + H1_OFF + (16 + l16) * H1_ST + (k0 + lk * 8) * 2);
        #pragma unroll
        for (int n = 0; n < 4; ++n) {
            int col = wave * 64 + n * 16 + l16;
            bf16x8 b = ldsAB(smem + W2C_OFF + col * 64 + ((lk ^ (col & 3)) << 4));
            mfma16(acc2[0][n], a0, b);
            mfma16(acc2[1][n], a1, b);
        }
    }
    __syncthreads();
    #pragma unroll
    for (int m = 0; m < 2; ++m)
        #pragma unroll
        for (int n = 0; n < 4; ++n) {
            int col = wave * 64 + n * 16 + l16;
            #pragma unroll
            for (int e = 0; e < 4; ++e) {
                float v = fmaxf(acc2[m][n][e] + b2v[n], 0.f);
                *(unsigned short*)(smem + H2_OFF + (m * 16 + lk * 4 + e) * H2_ST + col * 2) = bf16u(v);
            }
        }
    {   // stage W3 (region is dead h1 space)
        const unsigned short* src = ws + WS_W3;
        for (int o = wave; o < 7; o += 4)
            gll16((const unsigned char*)src + o * 1024 + lane * 16, smem + W3_OFF + o * 1024);
    }
    __syncthreads();

    // ================= Stage 3: f = relu(h2 @ W3 + b3) (redundant per wave) =================
    f32x4 acc3[2] = {};
    #pragma unroll
    for (int c = 0; c < 7; ++c) {
        const int k0 = c * 32;
        bf16x8 a0 = ldsAB(smem + H2_OFF + (l16)      * H2_ST + (k0 + lk * 8) * 2);
        bf16x8 a1 = ldsAB(smem + H2_OFF + (16 + l16) * H2_ST + (k0 + lk * 8) * 2);
        bf16x8 b  = ldsAB(smem + W3_OFF + l16 * W3_ST + k0 * 2 + ((lk ^ (l16 & 3)) << 4));
        mfma16(acc3[0], a0, b);
        mfma16(acc3[1], a1, b);
    }
    if (wave == 0 && l16 < NB) {
        #pragma unroll
        for (int m = 0; m < 2; ++m)
            #pragma unroll
            for (int e = 0; e < 4; ++e) {
                float v = fmaxf(acc3[m][e] + b3v, 0.f);
                *(float*)(smem + F_OFF + (m * 16 + lk * 4 + e) * F_ST + l16 * 4) = v;
            }
    }
    __syncthreads();   // stage-3 LDS reads complete; f written

    // stage Wh (bf16) + bh (f32) into LDS
    for (int j = tid; j < (NB * NA) / 4; j += 256)   // 5790 x 8B
        *(uint64_t*)(smem + WH_OFF + j * 8) =
            *(const uint64_t*)((const unsigned char*)(ws + WS_WH) + j * 8);
    for (int j = tid; j < NA / 4; j += 256)          // 579 x 16B
        *(float4*)(smem + BH_OFF + j * 16) = ((const float4*)bhg)[j];
    __syncthreads();

    // ================= Stage 4: out = f @ Wh + bh (fp32 VALU, store-bound) =================
    #pragma unroll 1
    for (int rg = 0; rg < 8; ++rg) {
        float fv[4][10];
        #pragma unroll
        for (int rr = 0; rr < 4; ++rr) {
            const unsigned char* fb = smem + F_OFF + (rg * 4 + rr) * F_ST;
            f32x4 p0 = *(const f32x4*)(fb);
            f32x4 p1 = *(const f32x4*)(fb + 16);
            float2 p2 = *(const float2*)(fb + 32);
            fv[rr][0] = p0[0]; fv[rr][1] = p0[1]; fv[rr][2] = p0[2]; fv[rr][3] = p0[3];
            fv[rr][4] = p1[0]; fv[rr][5] = p1[1]; fv[rr][6] = p1[2]; fv[rr][7] = p1[3];
            fv[rr][8] = p2.x;  fv[rr][9] = p2.y;
        }
        for (int j = tid; j < 579; j += 256) {
            float4 bhv = *(const float4*)(smem + BH_OFF + j * 16);
            float ac[4][4];
            #pragma unroll
            for (int rr = 0; rr < 4; ++rr) {
                ac[rr][0] = bhv.x; ac[rr][1] = bhv.y; ac[rr][2] = bhv.z; ac[rr][3] = bhv.w;
            }
            #pragma unroll
            for (int k = 0; k < 10; ++k) {
                uint2 w = *(const uint2*)(smem + WH_OFF + k * WH_ST + j * 8);
                float w0 = __uint_as_float(w.x << 16);
                float w1 = __uint_as_float(w.x & 0xffff0000u);
                float w2 = __uint_as_float(w.y << 16);
                float w3 = __uint_as_float(w.y & 0xffff0000u);
                #pragma unroll
                for (int rr = 0; rr < 4; ++rr) {
                    ac[rr][0] = fmaf(fv[rr][k], w0, ac[rr][0]);
                    ac[rr][1] = fmaf(fv[rr][k], w1, ac[rr][1]);
                    ac[rr][2] = fmaf(fv[rr][k], w2, ac[rr][2]);
                    ac[rr][3] = fmaf(fv[rr][k], w3, ac[rr][3]);
                }
            }
            #pragma unroll
            for (int rr = 0; rr < 4; ++rr) {
                float4 o;
                o.x = ac[rr][0]; o.y = ac[rr][1]; o.z = ac[rr][2]; o.w = ac[rr][3];
                *(float4*)(out + (size_t)(row0 + rg * 4 + rr) * NA + j * 4) = o;
            }
        }
    }
}

extern "C" void kernel_launch(void* const* d_in, const int* in_sizes, int n_in,
                              void* d_out, int out_size, void* d_ws, size_t ws_size,
                              hipStream_t stream)
{
    const float* x  = (const float*)d_in[0];
    const float* W1 = (const float*)d_in[1];
    const float* b1 = (const float*)d_in[2];
    const float* W2 = (const float*)d_in[3];
    const float* b2 = (const float*)d_in[4];
    const float* W3 = (const float*)d_in[5];
    const float* b3 = (const float*)d_in[6];
    const float* Wh = (const float*)d_in[7];
    const float* bh = (const float*)d_in[8];
    unsigned short* ws = (unsigned short*)d_ws;
    float* out = (float*)d_out;

    if (ws_size < (size_t)WS_END * sizeof(unsigned short)) return;

    cvt_weights<<<dim3((WS_END + 255) / 256), dim3(256), 0, stream>>>(W1, W2, W3, Wh, ws);
    fused_mlp<<<dim3(BATCH / RB), dim3(256), 0, stream>>>(x, b1, b2, b3, bh, ws, out);
}

// Round 3
// 64.428 us; speedup vs baseline: 1.0869x; 1.0869x over previous
//
#include <hip/hip_runtime.h>
#include <hip/hip_bf16.h>
#include <stdint.h>

using f32x4  = __attribute__((ext_vector_type(4))) float;
using bf16x8 = __attribute__((ext_vector_type(8))) __bf16;
using u16x4  = __attribute__((ext_vector_type(4))) unsigned short;
using u16x8  = __attribute__((ext_vector_type(8))) unsigned short;

#define DEVFN static __device__ __forceinline__

// ---------------- problem dims ----------------
constexpr int IND = 384, N1 = 512, N2R = 216, N2 = 256, NB = 10, NA = 2316;
constexpr int BATCH = 16384;
constexpr int RB  = 64;            // rows per block
constexpr int NC1 = 12;            // stage-1 K chunks (384/32)
constexpr int NC2 = 16;            // stage-2 K chunks (512/32)
constexpr int K3  = 224;           // stage-3 padded K (7 steps of 32)

// ---------------- ws layout (u16 elements) ----------------
constexpr int WS_W1  = 0;                       // 12 chunks [512 col][32 k] swizzled
constexpr int WS_W2  = WS_W1 + NC1 * N1 * 32;   // 196608: 16 chunks [256 col][32 k]
constexpr int WS_W3  = WS_W2 + NC2 * N2 * 32;   // 327680: [16 col][224 k]
constexpr int WS_WH  = WS_W3 + 16 * K3;         // 331264: [10][2316] bf16
constexpr int WS_END = WS_WH + NB * NA;         // 354424

// ---------------- LDS layout (byte offsets), phase-reused ----------------
constexpr int XT_OFF = 0;      constexpr int XT_ST = 784;   // [64][392] bf16 = 50176
constexpr int W1A    = 53312;  constexpr int W1B   = 86080; // 2x32768, end 118848
constexpr int H1_OFF = 0;      constexpr int H1_ST = 1040;  // [64][520] bf16 = 66560
constexpr int W2A    = 66560;  constexpr int W2B   = 82944; // 2x16384, end 99328
constexpr int H2_OFF = 0;      constexpr int H2_ST = 528;   // [64][264] bf16 = 33792
constexpr int W3_OFF = 33792;                               // 7168, end 40960
constexpr int WH_OFF = 0;                                   // 46320
constexpr int BH_OFF = 46320;                               // 9264, end 55584
constexpr int F_OFF  = 55584;  constexpr int F_ST  = 48;    // [64][12] f32 = 3072, end 58656
constexpr int B1L    = 118848; // 512 f32
constexpr int B2L    = 120896; // 256 f32 (zero-padded)
constexpr int B3L    = 121920; // 16 f32 (zero-padded)
constexpr int LDS_SZ = 121984;

DEVFN unsigned short bf16u(float f) {
    __hip_bfloat16 h = __float2bfloat16(f);
    unsigned short u; __builtin_memcpy(&u, &h, 2); return u;
}

DEVFN void mfma16(f32x4& d, bf16x8 a, bf16x8 b) {
    d = __builtin_amdgcn_mfma_f32_16x16x32_bf16(a, b, d, 0, 0, 0);
}

DEVFN void gll16(const void* g, void* lds) {
    __builtin_amdgcn_global_load_lds((const __attribute__((address_space(1))) void*)g,
                                     (__attribute__((address_space(3))) void*)lds, 16, 0, 0);
}

DEVFN void wait_vm4() { asm volatile("s_waitcnt vmcnt(4)" ::: "memory"); }
DEVFN void wait_vm2() { asm volatile("s_waitcnt vmcnt(2)" ::: "memory"); }
DEVFN void wait_vm0() { asm volatile("s_waitcnt vmcnt(0)" ::: "memory"); }
DEVFN void wait_lgkm0() { asm volatile("s_waitcnt lgkmcnt(0)" ::: "memory"); }

// ============ pre-kernel: coalesced fp32 -> bf16 transposed/swizzled ws image ============
// dest element (chunk c, col, s): holds W[k = c*32 + ((s>>3)^(col&3))*8 + (s&7)][col]
// inverse: source (c, o', s7) -> dest s = (o'^(col&3))*8 + s7  (16B-aligned oct stores)
__global__ __launch_bounds__(256)
void cvt_weights(const float* __restrict__ W1, const float* __restrict__ W2,
                 const float* __restrict__ W3, const float* __restrict__ Wh,
                 unsigned short* __restrict__ ws)
{
    const int bid = blockIdx.x, tid = threadIdx.x;
    if (bid < 12) {                        // W1 chunk: [384][512] source, coalesced rows
        const int c = bid;
        #pragma unroll
        for (int half = 0; half < 2; ++half) {
            const int col = half * 256 + tid;
            #pragma unroll
            for (int o = 0; o < 4; ++o) {
                u16x8 v;
                #pragma unroll
                for (int s7 = 0; s7 < 8; ++s7) {
                    int k = c * 32 + o * 8 + s7;
                    v[s7] = bf16u(W1[(size_t)k * N1 + col]);
                }
                *(u16x8*)(ws + WS_W1 + c * 16384 + col * 32 + ((o ^ (col & 3)) << 3)) = v;
            }
        }
    } else if (bid < 28) {                 // W2 chunk: [512][216] source
        const int c = bid - 12;
        const int col = tid;               // 0..255
        #pragma unroll
        for (int o = 0; o < 4; ++o) {
            u16x8 v;
            #pragma unroll
            for (int s7 = 0; s7 < 8; ++s7) {
                int k = c * 32 + o * 8 + s7;
                v[s7] = (col < N2R) ? bf16u(W2[(size_t)k * N2R + col]) : (unsigned short)0;
            }
            *(u16x8*)(ws + WS_W2 + c * 8192 + col * 32 + ((o ^ (col & 3)) << 3)) = v;
        }
    } else if (bid == 28) {                // W3: tiny, scalar
        for (int i = tid; i < 16 * K3; i += 256) {
            int col = i / K3, s = i - col * K3;
            int sb = s >> 5, r = s & 31;
            int k = sb * 32 + (((r >> 3) ^ (col & 3)) << 3) + (r & 7);
            float v = (col < NB && k < 216) ? W3[k * NB + col] : 0.f;
            ws[WS_W3 + i] = bf16u(v);
        }
    } else {                               // Wh: linear copy, 8 elems/thread
        int chunk = (bid - 29) * 256 + tid;        // of 2895
        if (chunk < (NB * NA) / 8) {
            const float4* s = (const float4*)(Wh + chunk * 8);
            float4 p0 = s[0], p1 = s[1];
            u16x8 v;
            v[0]=bf16u(p0.x); v[1]=bf16u(p0.y); v[2]=bf16u(p0.z); v[3]=bf16u(p0.w);
            v[4]=bf16u(p1.x); v[5]=bf16u(p1.y); v[6]=bf16u(p1.z); v[7]=bf16u(p1.w);
            *(u16x8*)(ws + WS_WH + chunk * 8) = v;
        }
    }
}

// ============ fused MLP: one block = 64 rows through all 4 layers ============
__global__ __launch_bounds__(512)
void fused_mlp(const float* __restrict__ x,
               const float* __restrict__ b1g, const float* __restrict__ b2g,
               const float* __restrict__ b3g, const float* __restrict__ bhg,
               const unsigned short* __restrict__ ws,
               float* __restrict__ out)
{
    __shared__ __attribute__((aligned(16))) unsigned char smem[LDS_SZ];
    const int tid  = threadIdx.x;
    const int wave = tid >> 6;
    const int lane = tid & 63;
    const int l16  = lane & 15;
    const int lk   = lane >> 4;
    const int wr   = wave >> 2;     // row-half (0,1)
    const int wc   = wave & 3;      // col-quarter
    const int row0 = blockIdx.x * RB;

    // ---- stage x tile [64][384] f32 -> bf16 LDS, + biases -> LDS ----
    {
        const float4* xg = (const float4*)(x + (size_t)row0 * IND);
        #pragma unroll
        for (int i = 0; i < 12; ++i) {
            int j = tid + i * 512;          // 0..6143
            float4 v = xg[j];
            int el = j * 4, r = el / IND, c = el - r * IND;
            u16x4 h;
            h[0] = bf16u(v.x); h[1] = bf16u(v.y); h[2] = bf16u(v.z); h[3] = bf16u(v.w);
            *(u16x4*)(smem + XT_OFF + r * XT_ST + c * 2) = h;
        }
        *(float*)(smem + B1L + tid * 4) = b1g[tid];
        if (tid < 256) *(float*)(smem + B2L + tid * 4) = (tid < N2R) ? b2g[tid] : 0.f;
        if (tid < 16)  *(float*)(smem + B3L + tid * 4) = (tid < NB)  ? b3g[tid] : 0.f;
    }
    __syncthreads();   // full drain: vmcnt clean before counted pipeline

    // ================= Stage 1: h1 = relu(x @ W1 + b1) =================
    const unsigned char* wsW1 = (const unsigned char*)(ws + WS_W1);
    f32x4 acc1[2][8] = {};

    // prologue: chunk 0 -> W1A (4 loads/thread)
    #pragma unroll
    for (int o = 0; o < 4; ++o) {
        int wb = o * 8192 + wave * 1024;
        gll16(wsW1 + wb + lane * 16, smem + W1A + wb);
    }
    for (int c = 0; c < NC1; ++c) {
        const int cur = (c & 1) ? W1B : W1A;
        if (c + 1 < NC1) {
            const unsigned char* src = wsW1 + (size_t)(c + 1) * 32768;
            const int nxt = (c & 1) ? W1A : W1B;
            #pragma unroll
            for (int o = 0; o < 4; ++o) {
                int wb = o * 8192 + wave * 1024;
                gll16(src + wb + lane * 16, smem + nxt + wb);
            }
            wait_vm4();
        } else {
            wait_vm0();
        }
        __builtin_amdgcn_s_barrier();
        const int k0 = c * 32;
        bf16x8 a0 = *(const bf16x8*)(smem + XT_OFF + (wr * 32 + l16)      * XT_ST + (k0 + lk * 8) * 2);
        bf16x8 a1 = *(const bf16x8*)(smem + XT_OFF + (wr * 32 + 16 + l16) * XT_ST + (k0 + lk * 8) * 2);
        #pragma unroll
        for (int n = 0; n < 8; ++n) {
            int col = wc * 128 + n * 16 + l16;
            bf16x8 b = *(const bf16x8*)(smem + cur + col * 64 + ((lk ^ (col & 3)) << 4));
            mfma16(acc1[0][n], a0, b);
            mfma16(acc1[1][n], a1, b);
        }
        __builtin_amdgcn_s_barrier();
    }
    // epilogue: acc -> relu+bias -> H1 (overlaps dead XT/W1 regions; reads done)
    #pragma unroll
    for (int m = 0; m < 2; ++m)
        #pragma unroll
        for (int n = 0; n < 8; ++n) {
            int col = wc * 128 + n * 16 + l16;
            float bias = *(const float*)(smem + B1L + col * 4);
            #pragma unroll
            for (int e = 0; e < 4; ++e) {
                float v = fmaxf(acc1[m][n][e] + bias, 0.f);
                *(unsigned short*)(smem + H1_OFF + (wr * 32 + m * 16 + lk * 4 + e) * H1_ST + col * 2) = bf16u(v);
            }
        }
    wait_lgkm0();
    __builtin_amdgcn_s_barrier();

    // ================= Stage 2: h2 = relu(h1 @ W2 + b2), N padded to 256 =================
    const unsigned char* wsW2 = (const unsigned char*)(ws + WS_W2);
    f32x4 acc2[2][4] = {};

    #pragma unroll
    for (int o = 0; o < 2; ++o) {          // prologue chunk 0 -> W2A
        int wb = o * 8192 + wave * 1024;
        gll16(wsW2 + wb + lane * 16, smem + W2A + wb);
    }
    for (int c = 0; c < NC2; ++c) {
        const int cur = (c & 1) ? W2B : W2A;
        if (c + 1 < NC2) {
            const unsigned char* src = wsW2 + (size_t)(c + 1) * 16384;
            const int nxt = (c & 1) ? W2A : W2B;
            #pragma unroll
            for (int o = 0; o < 2; ++o) {
                int wb = o * 8192 + wave * 1024;
                gll16(src + wb + lane * 16, smem + nxt + wb);
            }
            wait_vm2();
        } else {
            wait_vm0();
        }
        __builtin_amdgcn_s_barrier();
        const int k0 = c * 32;
        bf16x8 a0 = *(const bf16x8*)(smem + H1_OFF + (wr * 32 + l16)      * H1_ST + (k0 + lk * 8) * 2);
        bf16x8 a1 = *(const bf16x8*)(smem + H1_OFF + (wr * 32 + 16 + l16) * H1_ST + (k0 + lk * 8) * 2);
        #pragma unroll
        for (int n = 0; n < 4; ++n) {
            int col = wc * 64 + n * 16 + l16;
            bf16x8 b = *(const bf16x8*)(smem + cur + col * 64 + ((lk ^ (col & 3)) << 4));
            mfma16(acc2[0][n], a0, b);
            mfma16(acc2[1][n], a1, b);
        }
        __builtin_amdgcn_s_barrier();
    }
    // epilogue -> H2; also start W3 stage (dest disjoint from H2, old-H1 is dead)
    #pragma unroll
    for (int m = 0; m < 2; ++m)
        #pragma unroll
        for (int n = 0; n < 4; ++n) {
            int col = wc * 64 + n * 16 + l16;
            float bias = *(const float*)(smem + B2L + col * 4);
            #pragma unroll
            for (int e = 0; e < 4; ++e) {
                float v = fmaxf(acc2[m][n][e] + bias, 0.f);
                *(unsigned short*)(smem + H2_OFF + (wr * 32 + m * 16 + lk * 4 + e) * H2_ST + col * 2) = bf16u(v);
            }
        }
    if (wave < 7)
        gll16((const unsigned char*)(ws + WS_W3) + wave * 1024 + lane * 16, smem + W3_OFF + wave * 1024);
    __syncthreads();   // full drain (incl. W3 loads)

    // ================= Stage 3: f = relu(h2 @ W3 + b3) (redundant across wc) =================
    f32x4 acc3[2] = {};
    #pragma unroll
    for (int c = 0; c < 7; ++c) {
        const int k0 = c * 32;
        bf16x8 a0 = *(const bf16x8*)(smem + H2_OFF + (wr * 32 + l16)      * H2_ST + (k0 + lk * 8) * 2);
        bf16x8 a1 = *(const bf16x8*)(smem + H2_OFF + (wr * 32 + 16 + l16) * H2_ST + (k0 + lk * 8) * 2);
        bf16x8 b  = *(const bf16x8*)(smem + W3_OFF + l16 * 448 + c * 64 + ((lk ^ (l16 & 3)) << 4));
        mfma16(acc3[0], a0, b);
        mfma16(acc3[1], a1, b);
    }
    if (wc == 0 && l16 < NB) {
        float bias = *(const float*)(smem + B3L + l16 * 4);
        #pragma unroll
        for (int m = 0; m < 2; ++m)
            #pragma unroll
            for (int e = 0; e < 4; ++e) {
                float v = fmaxf(acc3[m][e] + bias, 0.f);
                *(float*)(smem + F_OFF + (wr * 32 + m * 16 + lk * 4 + e) * F_ST + l16 * 4) = v;
            }
    }
    __syncthreads();   // stage-3 reads done; F visible

    // stage Wh (bf16) + bh (f32) into LDS (overwrites dead H2/W3 regions)
    for (int j = tid; j < (NB * NA) / 4; j += 512)   // 5790 x 8B
        *(uint64_t*)(smem + WH_OFF + j * 8) =
            *(const uint64_t*)((const unsigned char*)(ws + WS_WH) + j * 8);
    for (int j = tid; j < NA / 4; j += 512)          // 579 x 16B
        *(float4*)(smem + BH_OFF + j * 16) = ((const float4*)bhg)[j];
    __syncthreads();

    // ================= Stage 4: out = f @ Wh + bh (fp32 VALU, store-bound) =================
    #pragma unroll 1
    for (int rg = 0; rg < 16; ++rg) {
        float fv[4][10];
        #pragma unroll
        for (int rr = 0; rr < 4; ++rr) {
            const unsigned char* fb = smem + F_OFF + (rg * 4 + rr) * F_ST;
            f32x4 p0 = *(const f32x4*)(fb);
            f32x4 p1 = *(const f32x4*)(fb + 16);
            float2 p2 = *(const float2*)(fb + 32);
            fv[rr][0] = p0[0]; fv[rr][1] = p0[1]; fv[rr][2] = p0[2]; fv[rr][3] = p0[3];
            fv[rr][4] = p1[0]; fv[rr][5] = p1[1]; fv[rr][6] = p1[2]; fv[rr][7] = p1[3];
            fv[rr][8] = p2.x;  fv[rr][9] = p2.y;
        }
        for (int j = tid; j < 579; j += 512) {
            float4 bhv = *(const float4*)(smem + BH_OFF + j * 16);
            float ac[4][4];
            #pragma unroll
            for (int rr = 0; rr < 4; ++rr) {
                ac[rr][0] = bhv.x; ac[rr][1] = bhv.y; ac[rr][2] = bhv.z; ac[rr][3] = bhv.w;
            }
            #pragma unroll
            for (int k = 0; k < 10; ++k) {
                uint2 w = *(const uint2*)(smem + WH_OFF + (k * NA + j * 4) * 2);
                float w0 = __uint_as_float(w.x << 16);
                float w1 = __uint_as_float(w.x & 0xffff0000u);
                float w2 = __uint_as_float(w.y << 16);
                float w3 = __uint_as_float(w.y & 0xffff0000u);
                #pragma unroll
                for (int rr = 0; rr < 4; ++rr) {
                    ac[rr][0] = fmaf(fv[rr][k], w0, ac[rr][0]);
                    ac[rr][1] = fmaf(fv[rr][k], w1, ac[rr][1]);
                    ac[rr][2] = fmaf(fv[rr][k], w2, ac[rr][2]);
                    ac[rr][3] = fmaf(fv[rr][k], w3, ac[rr][3]);
                }
            }
            #pragma unroll
            for (int rr = 0; rr < 4; ++rr) {
                float4 o;
                o.x = ac[rr][0]; o.y = ac[rr][1]; o.z = ac[rr][2]; o.w = ac[rr][3];
                *(float4*)(out + (size_t)(row0 + rg * 4 + rr) * NA + j * 4) = o;
            }
        }
    }
}

extern "C" void kernel_launch(void* const* d_in, const int* in_sizes, int n_in,
                              void* d_out, int out_size, void* d_ws, size_t ws_size,
                              hipStream_t stream)
{
    const float* x  = (const float*)d_in[0];
    const float* W1 = (const float*)d_in[1];
    const float* b1 = (const float*)d_in[2];
    const float* W2 = (const float*)d_in[3];
    const float* b2 = (const float*)d_in[4];
    const float* W3 = (const float*)d_in[5];
    const float* b3 = (const float*)d_in[6];
    const float* Wh = (const float*)d_in[7];
    const float* bh = (const float*)d_in[8];
    unsigned short* ws = (unsigned short*)d_ws;
    float* out = (float*)d_out;

    if (ws_size < (size_t)WS_END * sizeof(unsigned short)) return;

    cvt_weights<<<dim3(41), dim3(256), 0, stream>>>(W1, W2, W3, Wh, ws);
    fused_mlp<<<dim3(BATCH / RB), dim3(512), 0, stream>>>(x, b1, b2, b3, bh, ws, out);
}